// Round 14
// baseline (209.070 us; speedup 1.0000x reference)
//
#include <hip/hip_runtime.h>
#include <hip/hip_fp16.h>

// GCN 2-layer forward, CSR-gather with fixed-capacity radix binning.
// Bucket = dst >> 8  (391 buckets x 256 nodes), fixed region of CAP_B slots.
//   (memset) : zero bucket counters
//   k_binA   : LDS-staged bucket sort -> coalesced record writes
//   k_binB   : per-bucket CSR build in LDS -> esrc (in-place), start, cnt, dinv
//   k_xw     : xws = f16((x @ W1) * dinv)  [f16 W1 in LDS, XOR-swizzled granules]
//   k_gather1 : half2 gather (8-way edge split, MLP-8); h, hsc = f16(h*dinv)
//   k_gather2h: half2 gather over hsc; fused W2 epilogue
// d_out = [out (N*32) | h (N*16)]

#define NN 100000
#define NE 3200000
#define FIN 512
#define HID 16
#define NCLS 32
#define NB 391          // ceil(NN/256)
#define NBP 512         // padded bucket slots
#define CAP_B 9216      // fixed slots per bucket (mean 8184, +11 sigma)

// workspace element offsets (4-byte units)
#define OFF_BCNT  0                     // int [NBP]
#define OFF_START (NBP)                 // int [NN]
#define OFF_CNT   (NBP + NN)            // int [NN]
#define OFF_DINV  (NBP + 2*NN)          // float [NN]
#define OFF_EP    (NBP + 3*NN)          // u32 [NB*CAP_B]; becomes esrc
#define OFF_XWS   (OFF_EP + NB*CAP_B)   // half [NN*16] = NN*8 words
#define OFF_HSC   (OFF_XWS + NN*8)      // half [NN*16] = NN*8 words

// Bin edges. 512 thr/block, 8 edges/thread, 4096/block, 782 blocks.
// Records staged in LDS grouped by bucket -> global writes are coalesced runs.
__global__ __launch_bounds__(512) void k_binA(const int* __restrict__ src,
                                              const int* __restrict__ dst,
                                              int* __restrict__ bcnt,
                                              unsigned* __restrict__ ep) {
    __shared__ int hist[NBP];
    __shared__ int lstart[NBP];
    __shared__ int gpos[NBP];
    __shared__ unsigned recs[4096];
    __shared__ unsigned short bkt[4096];
    int tid = threadIdx.x;
    hist[tid] = 0;
    __syncthreads();
    int base = blockIdx.x * 4096;
    unsigned rec[8];
    int bk[8], pl[8];
#pragma unroll
    for (int k = 0; k < 8; ++k) {
        int e = base + tid + k * 512;
        if (e < NE) {
            int s = __builtin_nontemporal_load(src + e);
            int d = __builtin_nontemporal_load(dst + e);
            bk[k] = d >> 8;
            pl[k] = atomicAdd(&hist[bk[k]], 1);
            rec[k] = ((unsigned)s << 8) | (unsigned)(d & 255);
        } else bk[k] = -1;
    }
    __syncthreads();
    int v = hist[tid];
    lstart[tid] = v;
    __syncthreads();
#pragma unroll
    for (int o = 1; o < 512; o <<= 1) {
        int u = (tid >= o) ? lstart[tid - o] : 0;
        __syncthreads();
        lstart[tid] += u;
        __syncthreads();
    }
    int ex = lstart[tid] - v;           // exclusive local start
    if (v > 0) gpos[tid] = atomicAdd(&bcnt[tid], v);   // global reservation
    __syncthreads();
    lstart[tid] = ex;
    __syncthreads();
#pragma unroll
    for (int k = 0; k < 8; ++k) {
        if (bk[k] >= 0) {
            int slot = lstart[bk[k]] + pl[k];
            recs[slot] = rec[k];
            bkt[slot] = (unsigned short)bk[k];
        }
    }
    __syncthreads();
    int total = lstart[NBP - 1] + hist[NBP - 1];
#pragma unroll 2
    for (int t = tid; t < total; t += 512) {
        int b = bkt[t];
        ep[b * CAP_B + gpos[b] + (t - lstart[b])] = recs[t];
    }
}

// Per-bucket CSR build in LDS. Block b owns nodes [b*256, b*256+256).
__global__ __launch_bounds__(256) void k_binB(unsigned* __restrict__ ep,
                                              const int* __restrict__ bcnt,
                                              int* __restrict__ startA,
                                              int* __restrict__ cntA,
                                              float* __restrict__ dinv) {
    __shared__ int nh[256];
    __shared__ int ns[256];
    __shared__ int np_[256];
    __shared__ int esL[CAP_B];
    int tid = threadIdx.x;
    int b = blockIdx.x;
    int gbase = b * CAP_B;
    int bc = bcnt[b];
    if (bc > CAP_B) bc = CAP_B;         // defensive clamp
    nh[tid] = 0;
    __syncthreads();
    for (int t = tid; t < bc; t += 256)
        atomicAdd(&nh[ep[gbase + t] & 255], 1);
    __syncthreads();
    int v = nh[tid];
    ns[tid] = v;
    __syncthreads();
#pragma unroll
    for (int o = 1; o < 256; o <<= 1) {
        int u = (tid >= o) ? ns[tid - o] : 0;
        __syncthreads();
        ns[tid] += u;
        __syncthreads();
    }
    int ex = ns[tid] - v;               // exclusive start within bucket
    np_[tid] = ex;
    __syncthreads();
    for (int t = tid; t < bc; t += 256) {
        unsigned r = ep[gbase + t];
        int dl = r & 255;
        int p = atomicAdd(&np_[dl], 1);
        esL[p] = (int)(r >> 8);
    }
    __syncthreads();
    for (int t = tid; t < bc; t += 256)
        ep[gbase + t] = (unsigned)esL[t];   // in-place: ep becomes esrc
    int node = b * 256 + tid;
    if (node < NN) {
        startA[node] = gbase + ex;
        cntA[node]   = v;
        dinv[node]   = rsqrtf((float)(v + 1));
    }
}

// GEMM1: 4-way k-split, 2 nodes/thread. W1 in LDS as f16 pairs (half2 per
// k-pair), 16B-granule XOR swizzle keeps the 4 c-groups on disjoint bank
// quads. Per 4-k iter: 8 ds_read_b128 (was 16 f32) -> LDS no longer binding.
// Layout: element (k,j): kp=k>>1, u=kp*4+(j>>2), u'=u^((u>>3)&7),
//         byte = u'*16 + (j&3)*4 + (k&1)*2.
__global__ __launch_bounds__(256) void k_xw(const float* __restrict__ x,
                                            const float* __restrict__ W1,
                                            const float* __restrict__ dinv,
                                            __half* __restrict__ xws) {
    __shared__ float4 w1h[1024];        // 16 KB of f16, swizzled granules
    for (int t = threadIdx.x; t < FIN * HID; t += 256) {
        int k = t >> 4, j = t & 15;
        int u = (k >> 1) * 4 + (j >> 2);
        int us = u ^ ((u >> 3) & 7);
        char* p = (char*)w1h + us * 16 + (j & 3) * 4 + (k & 1) * 2;
        *(__half*)p = __float2half(W1[t]);
    }
    __syncthreads();
    int w  = threadIdx.x >> 6;          // wave in block (0..3)
    int nl = (threadIdx.x >> 2) & 15;   // node slot
    int c  = threadIdx.x & 3;           // k-split group
    int n0 = blockIdx.x * 128 + w * 32 + nl;
    int n1 = n0 + 16;
    bool v0 = n0 < NN, v1 = n1 < NN;
    const float4* x4 = reinterpret_cast<const float4*>(x);
    const float4* r0 = x4 + (v0 ? (size_t)n0 * (FIN / 4) : 0);
    const float4* r1 = x4 + (v1 ? (size_t)n1 * (FIN / 4) : 0);
    float a0[HID], a1[HID];
#pragma unroll
    for (int j = 0; j < HID; ++j) { a0[j] = 0.f; a1[j] = 0.f; }
#pragma unroll 4
    for (int t = 0; t < 32; ++t) {
        int qk = c + 4 * t;             // float4-quad (4 k-values)
        float4 xv0 = r0[qk];
        float4 xv1 = r1[qk];
#pragma unroll
        for (int d = 0; d < 2; ++d) {   // k-pair within the quad
            int kp = 2 * qk + d;
            float ex0 = d ? xv0.z : xv0.x, ey0 = d ? xv0.w : xv0.y;
            float ex1 = d ? xv1.z : xv1.x, ey1 = d ? xv1.w : xv1.y;
#pragma unroll
            for (int jh = 0; jh < 2; ++jh) {
#pragma unroll
                for (int q = 0; q < 2; ++q) {
                    int u = kp * 4 + jh * 2 + q;
                    int us = u ^ ((u >> 3) & 7);
                    float4 fv = w1h[us];
                    const __half2* hp = reinterpret_cast<const __half2*>(&fv);
#pragma unroll
                    for (int m = 0; m < 4; ++m) {
                        float2 f = __half22float2(hp[m]);
                        int j = jh * 8 + q * 4 + m;
                        a0[j] += ex0 * f.x + ey0 * f.y;
                        a1[j] += ex1 * f.x + ey1 * f.y;
                    }
                }
            }
        }
    }
#pragma unroll
    for (int j = 0; j < HID; ++j) {
        a0[j] += __shfl_xor(a0[j], 1);
        a0[j] += __shfl_xor(a0[j], 2);
        a1[j] += __shfl_xor(a1[j], 1);
        a1[j] += __shfl_xor(a1[j], 2);
    }
    if (c == 0) {
        if (v0) {
            float dv = dinv[n0];
            __half2 hv[8];
#pragma unroll
            for (int k = 0; k < 8; ++k)
                hv[k] = __floats2half2_rn(a0[2 * k] * dv, a0[2 * k + 1] * dv);
            float4* o = reinterpret_cast<float4*>(xws + (size_t)n0 * HID);
            o[0] = *reinterpret_cast<float4*>(&hv[0]);
            o[1] = *reinterpret_cast<float4*>(&hv[4]);
        }
        if (v1) {
            float dv = dinv[n1];
            __half2 hv[8];
#pragma unroll
            for (int k = 0; k < 8; ++k)
                hv[k] = __floats2half2_rn(a1[2 * k] * dv, a1[2 * k + 1] * dv);
            float4* o = reinterpret_cast<float4*>(xws + (size_t)n1 * HID);
            o[0] = *reinterpret_cast<float4*>(&hv[0]);
            o[1] = *reinterpret_cast<float4*>(&hv[4]);
        }
    }
}

// Gather layer 1: 1 node/wave. j2 = lane&7 (feature PAIR via __half2),
// c = lane>>3 (8-way edge split), MLP-8 -> 64 edges in flight per wave.
__global__ __launch_bounds__(256) void k_gather1(const int* __restrict__ startA,
                                                 const int* __restrict__ cntA,
                                                 const int* __restrict__ esrc,
                                                 const __half2* __restrict__ xws2,
                                                 const float* __restrict__ dinv,
                                                 const float* __restrict__ b1,
                                                 float* __restrict__ hout,
                                                 __half2* __restrict__ hsc2) {
    int wave = (blockIdx.x * 256 + threadIdx.x) >> 6;
    if (wave >= NN) return;
    int i = wave;
    int lane = threadIdx.x & 63;
    int j2 = lane & 7;
    int c = lane >> 3;                  // 0..7
    int st = startA[i], en = st + cntA[i];
    float sx[8], sy[8];
#pragma unroll
    for (int k = 0; k < 8; ++k) { sx[k] = 0.f; sy[k] = 0.f; }
    for (int e = st + c; e < en; e += 64) {
        int a[8];
#pragma unroll
        for (int k = 0; k < 8; ++k) {
            int ee = e + 8 * k;
            a[k] = __builtin_nontemporal_load(esrc + (ee < en ? ee : e));
        }
#pragma unroll
        for (int k = 0; k < 8; ++k) {
            float2 f = __half22float2(xws2[a[k] * 8 + j2]);
            bool ok = (e + 8 * k) < en;
            sx[k] += ok ? f.x : 0.f;
            sy[k] += ok ? f.y : 0.f;
        }
    }
    float sumx = ((sx[0] + sx[1]) + (sx[2] + sx[3])) + ((sx[4] + sx[5]) + (sx[6] + sx[7]));
    float sumy = ((sy[0] + sy[1]) + (sy[2] + sy[3])) + ((sy[4] + sy[5]) + (sy[6] + sy[7]));
    sumx += __shfl_xor(sumx, 8);  sumy += __shfl_xor(sumy, 8);
    sumx += __shfl_xor(sumx, 16); sumy += __shfl_xor(sumy, 16);
    sumx += __shfl_xor(sumx, 32); sumy += __shfl_xor(sumy, 32);
    if (c == 0) {
        float dv = dinv[i];
        float2 self = __half22float2(xws2[i * 8 + j2]);
        float vx = b1[2 * j2]     + dv * (sumx + self.x);
        float vy = b1[2 * j2 + 1] + dv * (sumy + self.y);
        float hx = vx > 0.f ? vx : 0.f;
        float hy = vy > 0.f ? vy : 0.f;
        *reinterpret_cast<float2*>(hout + i * HID + 2 * j2) = make_float2(hx, hy);
        hsc2[i * 8 + j2] = __floats2half2_rn(hx * dv, hy * dv);
    }
}

// Gather layer 2 with fused W2: same half2 MLP-8 structure over hsc.
__global__ __launch_bounds__(256) void k_gather2h(const int* __restrict__ startA,
                                                  const int* __restrict__ cntA,
                                                  const int* __restrict__ esrc,
                                                  const __half2* __restrict__ hsc2,
                                                  const float* __restrict__ dinv,
                                                  const float* __restrict__ W2,
                                                  const float* __restrict__ b2,
                                                  float* __restrict__ out) {
    __shared__ float w2s[HID * NCLS];
    __shared__ float b2s[NCLS];
    for (int t = threadIdx.x; t < HID * NCLS; t += 256) w2s[t] = W2[t];
    if (threadIdx.x < NCLS) b2s[threadIdx.x] = b2[threadIdx.x];
    __syncthreads();
    int wave = (blockIdx.x * 256 + threadIdx.x) >> 6;
    if (wave >= NN) return;
    int i = wave;
    int lane = threadIdx.x & 63;
    int j2 = lane & 7;
    int c = lane >> 3;                  // 0..7
    int st = startA[i], en = st + cntA[i];
    float sx[8], sy[8];
#pragma unroll
    for (int k = 0; k < 8; ++k) { sx[k] = 0.f; sy[k] = 0.f; }
    for (int e = st + c; e < en; e += 64) {
        int a[8];
#pragma unroll
        for (int k = 0; k < 8; ++k) {
            int ee = e + 8 * k;
            a[k] = __builtin_nontemporal_load(esrc + (ee < en ? ee : e));
        }
#pragma unroll
        for (int k = 0; k < 8; ++k) {
            float2 f = __half22float2(hsc2[a[k] * 8 + j2]);
            bool ok = (e + 8 * k) < en;
            sx[k] += ok ? f.x : 0.f;
            sy[k] += ok ? f.y : 0.f;
        }
    }
    float sumx = ((sx[0] + sx[1]) + (sx[2] + sx[3])) + ((sx[4] + sx[5]) + (sx[6] + sx[7]));
    float sumy = ((sy[0] + sy[1]) + (sy[2] + sy[3])) + ((sy[4] + sy[5]) + (sy[6] + sy[7]));
    sumx += __shfl_xor(sumx, 8);  sumy += __shfl_xor(sumy, 8);
    sumx += __shfl_xor(sumx, 16); sumy += __shfl_xor(sumy, 16);
    sumx += __shfl_xor(sumx, 32); sumy += __shfl_xor(sumy, 32);
    {   // self-loop term
        float2 self = __half22float2(hsc2[i * 8 + j2]);
        sumx += self.x;
        sumy += self.y;
    }
    int jo = lane & 31;
    float acc = 0.f;
#pragma unroll
    for (int p = 0; p < 8; ++p) {
        acc += __shfl(sumx, p) * w2s[(2 * p) * NCLS + jo];
        acc += __shfl(sumy, p) * w2s[(2 * p + 1) * NCLS + jo];
    }
    if (lane < 32)
        out[i * NCLS + jo] = b2s[jo] + dinv[i] * acc;
}

extern "C" void kernel_launch(void* const* d_in, const int* in_sizes, int n_in,
                              void* d_out, int out_size, void* d_ws, size_t ws_size,
                              hipStream_t stream) {
    const float* x  = (const float*)d_in[0];
    const int* ei   = (const int*)d_in[1];      // [2][NE]
    const float* W1 = (const float*)d_in[2];
    const float* b1 = (const float*)d_in[3];
    const float* W2 = (const float*)d_in[4];
    const float* b2 = (const float*)d_in[5];

    const int* src = ei;
    const int* dst = ei + NE;

    int* wsi = (int*)d_ws;
    int*      bcnt  = wsi + OFF_BCNT;
    int*      startA= wsi + OFF_START;
    int*      cntA  = wsi + OFF_CNT;
    float*    dinv  = (float*)(wsi + OFF_DINV);
    unsigned* ep    = (unsigned*)(wsi + OFF_EP);   // packed, then esrc
    __half*   xws   = (__half*)(wsi + OFF_XWS);
    __half2*  xws2  = (__half2*)(wsi + OFF_XWS);
    __half2*  hsc2  = (__half2*)(wsi + OFF_HSC);

    float* outp = (float*)d_out;           // [NN*32]
    float* hout = outp + NN * NCLS;        // [NN*16]

    const int B = 256;

    hipMemsetAsync(bcnt, 0, NBP * sizeof(int), stream);
    hipLaunchKernelGGL(k_binA,  dim3((NE + 4095) / 4096), dim3(512), 0, stream, src, dst, bcnt, ep);
    hipLaunchKernelGGL(k_binB,  dim3(NB), dim3(B), 0, stream, ep, bcnt, startA, cntA, dinv);
    hipLaunchKernelGGL(k_xw,    dim3((NN + 127) / 128), dim3(B), 0, stream, x, W1, dinv, xws);
    hipLaunchKernelGGL(k_gather1, dim3((NN * 64 + B - 1) / B), dim3(B), 0, stream,
                       startA, cntA, (const int*)ep, xws2, dinv, b1, hout, hsc2);
    hipLaunchKernelGGL(k_gather2h, dim3((NN * 64 + B - 1) / B), dim3(B), 0, stream,
                       startA, cntA, (const int*)ep, hsc2, dinv, W2, b2, outp);
}

// Round 15
// 193.302 us; speedup vs baseline: 1.0816x; 1.0816x over previous
//
#include <hip/hip_runtime.h>
#include <hip/hip_fp16.h>

// GCN 2-layer forward, CSR-gather with fixed-capacity radix binning.
// (R13 structure — proven 202.7 us — plus int2-packed (start,cnt).)
//   (memset) : zero bucket counters
//   k_binA   : scatter packed records (src<<8 | dstLocal); 782 blocks (3/CU)
//   k_binB   : per-bucket CSR build in LDS -> esrc (in-place), sc, dinv
//   k_xw     : xws = f16((x @ W1) * dinv)  [f32 W1 LDS, XOR-swizzled float4]
//   k_gather1 : half2 gather (8-way edge split, MLP-8); h, hsc = f16(h*dinv)
//   k_gather2h: half2 gather over hsc; fused W2 epilogue
// d_out = [out (N*32) | h (N*16)]

#define NN 100000
#define NE 3200000
#define FIN 512
#define HID 16
#define NCLS 32
#define NB 391          // ceil(NN/256)
#define NBP 512         // padded bucket slots
#define CAP_B 9216      // fixed slots per bucket (mean 8184, +11 sigma)

// workspace element offsets (4-byte units)
#define OFF_BCNT  0                     // int [NBP]
#define OFF_SC    (NBP)                 // int2 [NN]  (start, cnt)
#define OFF_DINV  (NBP + 2*NN)          // float [NN]
#define OFF_EP    (NBP + 3*NN)          // u32 [NB*CAP_B]; becomes esrc
#define OFF_XWS   (OFF_EP + NB*CAP_B)   // half [NN*16] = NN*8 words
#define OFF_HSC   (OFF_XWS + NN*8)      // half [NN*16] = NN*8 words

// Bin edges into fixed-cap bucket regions. 512 thr/block, 8 edges/thread,
// 4096 edges/block, 782 blocks (~3/CU).
__global__ __launch_bounds__(512) void k_binA(const int* __restrict__ src,
                                              const int* __restrict__ dst,
                                              int* __restrict__ bcnt,
                                              unsigned* __restrict__ ep) {
    __shared__ int hist[NBP];
    __shared__ int gpos[NBP];
    int tid = threadIdx.x;
    hist[tid] = 0;
    __syncthreads();
    int base = blockIdx.x * 4096;
    unsigned rec[8];
    int meta[8];                        // (p_local << 9) | bucket, or -1
#pragma unroll
    for (int k = 0; k < 8; ++k) {
        int e = base + tid + k * 512;
        if (e < NE) {
            int s = __builtin_nontemporal_load(src + e);
            int d = __builtin_nontemporal_load(dst + e);
            int b = d >> 8;
            int p = atomicAdd(&hist[b], 1);
            rec[k] = ((unsigned)s << 8) | (unsigned)(d & 255);
            meta[k] = (p << 9) | b;
        } else meta[k] = -1;
    }
    __syncthreads();
    int v = hist[tid];
    if (v > 0) gpos[tid] = atomicAdd(&bcnt[tid], v);   // direct reservation
    __syncthreads();
#pragma unroll
    for (int k = 0; k < 8; ++k) {
        if (meta[k] >= 0) {
            int b = meta[k] & 511;
            int p = meta[k] >> 9;
            ep[b * CAP_B + gpos[b] + p] = rec[k];
        }
    }
}

// Per-bucket CSR build in LDS. Block b owns nodes [b*256, b*256+256).
__global__ __launch_bounds__(256) void k_binB(unsigned* __restrict__ ep,
                                              const int* __restrict__ bcnt,
                                              int2* __restrict__ sc,
                                              float* __restrict__ dinv) {
    __shared__ int nh[256];
    __shared__ int ns[256];
    __shared__ int np_[256];
    __shared__ int esL[CAP_B];
    int tid = threadIdx.x;
    int b = blockIdx.x;
    int gbase = b * CAP_B;
    int bc = bcnt[b];
    if (bc > CAP_B) bc = CAP_B;         // defensive clamp
    nh[tid] = 0;
    __syncthreads();
    for (int t = tid; t < bc; t += 256)
        atomicAdd(&nh[ep[gbase + t] & 255], 1);
    __syncthreads();
    int v = nh[tid];
    ns[tid] = v;
    __syncthreads();
#pragma unroll
    for (int o = 1; o < 256; o <<= 1) {
        int u = (tid >= o) ? ns[tid - o] : 0;
        __syncthreads();
        ns[tid] += u;
        __syncthreads();
    }
    int ex = ns[tid] - v;               // exclusive start within bucket
    np_[tid] = ex;
    __syncthreads();
    for (int t = tid; t < bc; t += 256) {
        unsigned r = ep[gbase + t];
        int dl = r & 255;
        int p = atomicAdd(&np_[dl], 1);
        esL[p] = (int)(r >> 8);
    }
    __syncthreads();
    for (int t = tid; t < bc; t += 256)
        ep[gbase + t] = (unsigned)esL[t];   // in-place: ep becomes esrc
    int node = b * 256 + tid;
    if (node < NN) {
        sc[node] = make_int2(gbase + ex, v);
        dinv[node] = rsqrtf((float)(v + 1));
    }
}

// GEMM1: 4-way k-split, 2 nodes per thread; XOR-swizzled f32 W1 in LDS;
// f16 output. (R7-proven structure.)
__global__ __launch_bounds__(256) void k_xw(const float* __restrict__ x,
                                            const float* __restrict__ W1,
                                            const float* __restrict__ dinv,
                                            __half* __restrict__ xws) {
    __shared__ float w1[FIN * HID];     // 32 KB, XOR-swizzled float4 blocks
    for (int t = threadIdx.x; t < FIN * HID; t += 256) {
        int k = t >> 4, j = t & 15;
        int s = (k * 4 + ((j >> 2) ^ ((k >> 2) & 3))) * 4 + (j & 3);
        w1[s] = W1[t];
    }
    __syncthreads();
    int w  = threadIdx.x >> 6;          // wave in block (0..3)
    int nl = (threadIdx.x >> 2) & 15;   // node slot
    int c  = threadIdx.x & 3;           // k-split group
    int n0 = blockIdx.x * 128 + w * 32 + nl;
    int n1 = n0 + 16;
    bool v0 = n0 < NN, v1 = n1 < NN;
    const float4* x4 = reinterpret_cast<const float4*>(x);
    const float4* r0 = x4 + (v0 ? (size_t)n0 * (FIN / 4) : 0);
    const float4* r1 = x4 + (v1 ? (size_t)n1 * (FIN / 4) : 0);
    const float4* wv = reinterpret_cast<const float4*>(w1);
    float a0[HID], a1[HID];
#pragma unroll
    for (int j = 0; j < HID; ++j) { a0[j] = 0.f; a1[j] = 0.f; }
#pragma unroll 4
    for (int t = 0; t < 32; ++t) {
        int qk = c + 4 * t;             // float4-quad index into the row
        float4 xv0 = r0[qk];
        float4 xv1 = r1[qk];
        const float4* wb = wv + qk * 16;
#pragma unroll
        for (int e = 0; e < 4; ++e) {
            float xe0 = (e == 0) ? xv0.x : (e == 1) ? xv0.y : (e == 2) ? xv0.z : xv0.w;
            float xe1 = (e == 0) ? xv1.x : (e == 1) ? xv1.y : (e == 2) ? xv1.z : xv1.w;
#pragma unroll
            for (int j4 = 0; j4 < 4; ++j4) {
                float4 w4 = wb[e * 4 + (j4 ^ c)];   // true w1[k][j4*4..+3]
                a0[j4 * 4 + 0] += xe0 * w4.x;
                a0[j4 * 4 + 1] += xe0 * w4.y;
                a0[j4 * 4 + 2] += xe0 * w4.z;
                a0[j4 * 4 + 3] += xe0 * w4.w;
                a1[j4 * 4 + 0] += xe1 * w4.x;
                a1[j4 * 4 + 1] += xe1 * w4.y;
                a1[j4 * 4 + 2] += xe1 * w4.z;
                a1[j4 * 4 + 3] += xe1 * w4.w;
            }
        }
    }
#pragma unroll
    for (int j = 0; j < HID; ++j) {
        a0[j] += __shfl_xor(a0[j], 1);
        a0[j] += __shfl_xor(a0[j], 2);
        a1[j] += __shfl_xor(a1[j], 1);
        a1[j] += __shfl_xor(a1[j], 2);
    }
    if (c == 0) {
        if (v0) {
            float dv = dinv[n0];
            __half2 hv[8];
#pragma unroll
            for (int k = 0; k < 8; ++k)
                hv[k] = __floats2half2_rn(a0[2 * k] * dv, a0[2 * k + 1] * dv);
            float4* o = reinterpret_cast<float4*>(xws + (size_t)n0 * HID);
            o[0] = *reinterpret_cast<float4*>(&hv[0]);
            o[1] = *reinterpret_cast<float4*>(&hv[4]);
        }
        if (v1) {
            float dv = dinv[n1];
            __half2 hv[8];
#pragma unroll
            for (int k = 0; k < 8; ++k)
                hv[k] = __floats2half2_rn(a1[2 * k] * dv, a1[2 * k + 1] * dv);
            float4* o = reinterpret_cast<float4*>(xws + (size_t)n1 * HID);
            o[0] = *reinterpret_cast<float4*>(&hv[0]);
            o[1] = *reinterpret_cast<float4*>(&hv[4]);
        }
    }
}

// Gather layer 1: 1 node/wave. j2 = lane&7 (feature PAIR via __half2),
// c = lane>>3 (8-way edge split), MLP-8 -> 64 edges in flight per wave.
__global__ __launch_bounds__(256) void k_gather1(const int2* __restrict__ sc,
                                                 const int* __restrict__ esrc,
                                                 const __half2* __restrict__ xws2,
                                                 const float* __restrict__ dinv,
                                                 const float* __restrict__ b1,
                                                 float* __restrict__ hout,
                                                 __half2* __restrict__ hsc2) {
    int wave = (blockIdx.x * 256 + threadIdx.x) >> 6;
    if (wave >= NN) return;
    int i = wave;
    int lane = threadIdx.x & 63;
    int j2 = lane & 7;
    int c = lane >> 3;                  // 0..7
    int2 s2 = sc[i];
    int st = s2.x, en = st + s2.y;
    float sx[8], sy[8];
#pragma unroll
    for (int k = 0; k < 8; ++k) { sx[k] = 0.f; sy[k] = 0.f; }
    for (int e = st + c; e < en; e += 64) {
        int a[8];
#pragma unroll
        for (int k = 0; k < 8; ++k) {
            int ee = e + 8 * k;
            a[k] = __builtin_nontemporal_load(esrc + (ee < en ? ee : e));
        }
#pragma unroll
        for (int k = 0; k < 8; ++k) {
            float2 f = __half22float2(xws2[a[k] * 8 + j2]);
            bool ok = (e + 8 * k) < en;
            sx[k] += ok ? f.x : 0.f;
            sy[k] += ok ? f.y : 0.f;
        }
    }
    float sumx = ((sx[0] + sx[1]) + (sx[2] + sx[3])) + ((sx[4] + sx[5]) + (sx[6] + sx[7]));
    float sumy = ((sy[0] + sy[1]) + (sy[2] + sy[3])) + ((sy[4] + sy[5]) + (sy[6] + sy[7]));
    sumx += __shfl_xor(sumx, 8);  sumy += __shfl_xor(sumy, 8);
    sumx += __shfl_xor(sumx, 16); sumy += __shfl_xor(sumy, 16);
    sumx += __shfl_xor(sumx, 32); sumy += __shfl_xor(sumy, 32);
    if (c == 0) {
        float dv = dinv[i];
        float2 self = __half22float2(xws2[i * 8 + j2]);
        float vx = b1[2 * j2]     + dv * (sumx + self.x);
        float vy = b1[2 * j2 + 1] + dv * (sumy + self.y);
        float hx = vx > 0.f ? vx : 0.f;
        float hy = vy > 0.f ? vy : 0.f;
        *reinterpret_cast<float2*>(hout + i * HID + 2 * j2) = make_float2(hx, hy);
        hsc2[i * 8 + j2] = __floats2half2_rn(hx * dv, hy * dv);
    }
}

// Gather layer 2 with fused W2: same half2 MLP-8 structure over hsc.
__global__ __launch_bounds__(256) void k_gather2h(const int2* __restrict__ sc,
                                                  const int* __restrict__ esrc,
                                                  const __half2* __restrict__ hsc2,
                                                  const float* __restrict__ dinv,
                                                  const float* __restrict__ W2,
                                                  const float* __restrict__ b2,
                                                  float* __restrict__ out) {
    __shared__ float w2s[HID * NCLS];
    __shared__ float b2s[NCLS];
    for (int t = threadIdx.x; t < HID * NCLS; t += 256) w2s[t] = W2[t];
    if (threadIdx.x < NCLS) b2s[threadIdx.x] = b2[threadIdx.x];
    __syncthreads();
    int wave = (blockIdx.x * 256 + threadIdx.x) >> 6;
    if (wave >= NN) return;
    int i = wave;
    int lane = threadIdx.x & 63;
    int j2 = lane & 7;
    int c = lane >> 3;                  // 0..7
    int2 s2 = sc[i];
    int st = s2.x, en = st + s2.y;
    float sx[8], sy[8];
#pragma unroll
    for (int k = 0; k < 8; ++k) { sx[k] = 0.f; sy[k] = 0.f; }
    for (int e = st + c; e < en; e += 64) {
        int a[8];
#pragma unroll
        for (int k = 0; k < 8; ++k) {
            int ee = e + 8 * k;
            a[k] = __builtin_nontemporal_load(esrc + (ee < en ? ee : e));
        }
#pragma unroll
        for (int k = 0; k < 8; ++k) {
            float2 f = __half22float2(hsc2[a[k] * 8 + j2]);
            bool ok = (e + 8 * k) < en;
            sx[k] += ok ? f.x : 0.f;
            sy[k] += ok ? f.y : 0.f;
        }
    }
    float sumx = ((sx[0] + sx[1]) + (sx[2] + sx[3])) + ((sx[4] + sx[5]) + (sx[6] + sx[7]));
    float sumy = ((sy[0] + sy[1]) + (sy[2] + sy[3])) + ((sy[4] + sy[5]) + (sy[6] + sy[7]));
    sumx += __shfl_xor(sumx, 8);  sumy += __shfl_xor(sumy, 8);
    sumx += __shfl_xor(sumx, 16); sumy += __shfl_xor(sumy, 16);
    sumx += __shfl_xor(sumx, 32); sumy += __shfl_xor(sumy, 32);
    {   // self-loop term
        float2 self = __half22float2(hsc2[i * 8 + j2]);
        sumx += self.x;
        sumy += self.y;
    }
    int jo = lane & 31;
    float acc = 0.f;
#pragma unroll
    for (int p = 0; p < 8; ++p) {
        acc += __shfl(sumx, p) * w2s[(2 * p) * NCLS + jo];
        acc += __shfl(sumy, p) * w2s[(2 * p + 1) * NCLS + jo];
    }
    if (lane < 32)
        out[i * NCLS + jo] = b2s[jo] + dinv[i] * acc;
}

extern "C" void kernel_launch(void* const* d_in, const int* in_sizes, int n_in,
                              void* d_out, int out_size, void* d_ws, size_t ws_size,
                              hipStream_t stream) {
    const float* x  = (const float*)d_in[0];
    const int* ei   = (const int*)d_in[1];      // [2][NE]
    const float* W1 = (const float*)d_in[2];
    const float* b1 = (const float*)d_in[3];
    const float* W2 = (const float*)d_in[4];
    const float* b2 = (const float*)d_in[5];

    const int* src = ei;
    const int* dst = ei + NE;

    int* wsi = (int*)d_ws;
    int*      bcnt  = wsi + OFF_BCNT;
    int2*     sc    = (int2*)(wsi + OFF_SC);
    float*    dinv  = (float*)(wsi + OFF_DINV);
    unsigned* ep    = (unsigned*)(wsi + OFF_EP);   // packed, then esrc
    __half*   xws   = (__half*)(wsi + OFF_XWS);
    __half2*  xws2  = (__half2*)(wsi + OFF_XWS);
    __half2*  hsc2  = (__half2*)(wsi + OFF_HSC);

    float* outp = (float*)d_out;           // [NN*32]
    float* hout = outp + NN * NCLS;        // [NN*16]

    const int B = 256;

    hipMemsetAsync(bcnt, 0, NBP * sizeof(int), stream);
    hipLaunchKernelGGL(k_binA,  dim3((NE + 4095) / 4096), dim3(512), 0, stream, src, dst, bcnt, ep);
    hipLaunchKernelGGL(k_binB,  dim3(NB), dim3(B), 0, stream, ep, bcnt, sc, dinv);
    hipLaunchKernelGGL(k_xw,    dim3((NN + 127) / 128), dim3(B), 0, stream, x, W1, dinv, xws);
    hipLaunchKernelGGL(k_gather1, dim3((NN * 64 + B - 1) / B), dim3(B), 0, stream,
                       sc, (const int*)ep, xws2, dinv, b1, hout, hsc2);
    hipLaunchKernelGGL(k_gather2h, dim3((NN * 64 + B - 1) / B), dim3(B), 0, stream,
                       sc, (const int*)ep, hsc2, dinv, W2, b2, outp);
}